// Round 3
// baseline (805.280 us; speedup 1.0000x reference)
//
#include <hip/hip_runtime.h>

// ---------------------------------------------------------------------------
// LUNA fused pipeline for MI355X / gfx950.  B=16, S=4096, P=64, QKV=512, H=8.
// R3: projections are MEMORY-bound -> new gemm_fa: full-N 512 block tile,
//     A fp32 kept in registers (fp32->bf16 in-flight, conv kernel deleted),
//     B (L2-resident weight) via global_load_lds dbuf + single barrier/iter.
//     pack_attn split 4->8 chunks.
// ---------------------------------------------------------------------------

typedef __bf16 bf16x8 __attribute__((ext_vector_type(8)));
typedef float f32x4 __attribute__((ext_vector_type(4)));
typedef unsigned short u16x8 __attribute__((ext_vector_type(8)));
typedef unsigned short u16x4 __attribute__((ext_vector_type(4)));

#define MFMA16(a, b, c) __builtin_amdgcn_mfma_f32_16x16x32_bf16((a), (b), (c), 0, 0, 0)

__device__ __forceinline__ unsigned short f2bf_bits(float f) {
  unsigned int u = __float_as_uint(f);
  u += 0x7fffu + ((u >> 16) & 1u);  // RTNE (finite inputs)
  return (unsigned short)(u >> 16);
}

__device__ __forceinline__ void gload16(const unsigned short* g, unsigned short* l) {
  __builtin_amdgcn_global_load_lds(
      (const __attribute__((address_space(1))) void*)g,
      (__attribute__((address_space(3))) void*)l, 16, 0, 0);
}

// ---------------------------------------------------------------------------
// Batched transpose+convert of eight 512x512 fp32 weights -> bf16 W^T.
// ---------------------------------------------------------------------------
struct Ptr8 { const float* p[8]; };

__global__ __launch_bounds__(256) void transpose_w8(Ptr8 srcs,
                                                    unsigned short* __restrict__ WT) {
  const float* __restrict__ W = srcs.p[blockIdx.z];
  unsigned short* __restrict__ O = WT + (size_t)blockIdx.z * 262144;
  __shared__ float tile[32][33];
  const int t = threadIdx.x;
  const int tr = blockIdx.x * 32, tc = blockIdx.y * 32;
  {
    const int r = t >> 3, c4 = (t & 7) * 4;
    const float4 v = *reinterpret_cast<const float4*>(&W[(size_t)(tr + r) * 512 + tc + c4]);
    tile[r][c4 + 0] = v.x; tile[r][c4 + 1] = v.y; tile[r][c4 + 2] = v.z; tile[r][c4 + 3] = v.w;
  }
  __syncthreads();
  {
    const int n = t >> 3, k4 = (t & 7) * 4;
    u16x4 o;
#pragma unroll
    for (int j = 0; j < 4; j++) o[j] = f2bf_bits(tile[k4 + j][n]);
    *reinterpret_cast<u16x4*>(&O[(size_t)(tc + n) * 512 + tr + k4]) = o;
  }
}

// ---------------------------------------------------------------------------
// Batched combined biases: [bqe(512) | bpqe(512) | bpkve(1024)].
// ---------------------------------------------------------------------------
__global__ __launch_bounds__(256) void bias_all(
    const float* bi, const float* bip, const float* bic,
    const float* Wq, const float* Wpq, const float* Wpk, const float* Wpv,
    const float* bq, const float* bpq, const float* bpk, const float* bpv,
    float* __restrict__ out) {
  const int y = blockIdx.y;
  const float* bin  = (y == 0) ? bi : (y == 1) ? bip : bic;
  const float* W    = (y == 0) ? Wq : (y == 1) ? Wpq : (y == 2) ? Wpk : Wpv;
  const float* bout = (y == 0) ? bq : (y == 1) ? bpq : (y == 2) ? bpk : bpv;
  const float scale = (y < 2) ? 0.125f : 1.0f;
  const int n = blockIdx.x * 256 + threadIdx.x;
  float s = 0.f;
  for (int k = 0; k < 512; k++) s += bin[k] * W[(size_t)k * 512 + n];
  out[y * 512 + n] = (s + bout[n]) * scale;
}

// ---------------------------------------------------------------------------
// Batched weight-combine: out_z^T = scale_z * (A_z @ WT_z^T), z in 0..3.
// ---------------------------------------------------------------------------
__global__ __launch_bounds__(256) void gemm_wcomb(
    const float* __restrict__ Wi, const float* __restrict__ Wip,
    const float* __restrict__ Wic, const unsigned short* __restrict__ WTbase,
    unsigned short* __restrict__ outbase) {
  const int z = blockIdx.z;
  const float* __restrict__ A = (z == 0) ? Wi : (z == 1) ? Wip : Wic;
  const unsigned short* __restrict__ BT = WTbase + (size_t)z * 262144;
  unsigned short* __restrict__ out = outbase + (size_t)z * 262144;
  const float scale = (z < 2) ? 0.125f : 1.0f;

  __shared__ __align__(16) unsigned short As[128 * 72];
  __shared__ __align__(16) unsigned short Bs[128 * 72];
  const int t = threadIdx.x;
  const int w = t >> 6, l = t & 63, li = l & 15, lg = l >> 4;
  const int wm = w >> 1, wn = w & 1;
  const int m0 = blockIdx.x * 128, n0 = blockIdx.y * 128;

  f32x4 acc[4][4] = {};

  for (int kt = 0; kt < 512; kt += 64) {
#pragma unroll
    for (int i = 0; i < 8; i++) {
      const int row = i * 16 + (t >> 4), k = (t & 15) * 4;
      const float4 v = *reinterpret_cast<const float4*>(&A[(size_t)(m0 + row) * 512 + kt + k]);
      u16x4 o;
      o[0] = f2bf_bits(v.x); o[1] = f2bf_bits(v.y);
      o[2] = f2bf_bits(v.z); o[3] = f2bf_bits(v.w);
      *reinterpret_cast<u16x4*>(&As[row * 72 + k]) = o;
    }
#pragma unroll
    for (int i = 0; i < 4; i++) {
      const int row = i * 32 + (t >> 3), k = (t & 7) * 8;
      const u16x8 v = *reinterpret_cast<const u16x8*>(&BT[(size_t)(n0 + row) * 512 + kt + k]);
      *reinterpret_cast<u16x8*>(&Bs[row * 72 + k]) = v;
    }
    __syncthreads();
#pragma unroll
    for (int kk = 0; kk < 2; kk++) {
      bf16x8 a[4], b[4];
#pragma unroll
      for (int mf = 0; mf < 4; mf++)
        a[mf] = *reinterpret_cast<const bf16x8*>(&As[(wm * 64 + mf * 16 + li) * 72 + kk * 32 + lg * 8]);
#pragma unroll
      for (int nf = 0; nf < 4; nf++)
        b[nf] = *reinterpret_cast<const bf16x8*>(&Bs[(wn * 64 + nf * 16 + li) * 72 + kk * 32 + lg * 8]);
#pragma unroll
      for (int mf = 0; mf < 4; mf++)
#pragma unroll
        for (int nf = 0; nf < 4; nf++)
          acc[mf][nf] = MFMA16(a[mf], b[nf], acc[mf][nf]);
    }
    __syncthreads();
  }
  const int lg4 = lg * 4;
#pragma unroll
  for (int nf = 0; nf < 4; nf++) {
    const int col = n0 + wn * 64 + nf * 16 + li;
#pragma unroll
    for (int mf = 0; mf < 4; mf++) {
      const int row = m0 + wm * 64 + mf * 16 + lg4;
#pragma unroll
      for (int r = 0; r < 4; r++)
        out[(size_t)col * 512 + row + r] = f2bf_bits(acc[mf][nf][r] * scale);
    }
  }
}

// ---------------------------------------------------------------------------
// gemm_fa: C[M x (NT*512)] = A[M x 512] @ BT^T (+bias).  Memory-bound design:
// block tile 128M x 512N, 512 threads = 8 waves (2M x 4N), A fp32/bf16 held in
// REGISTERS (read exactly once per N-pass, converted in-flight), B staged via
// global_load_lds into double-buffered XOR-swizzled LDS (1 barrier / K-tile).
// 1D grid, n-pass fastest (the 2nd A pass hits L3).
// MODE 0: bf16 out + bias.  MODE 1: fp32 out + bias.
// ---------------------------------------------------------------------------
template <typename AT, int MODE, int NT>
__global__ __launch_bounds__(512) void gemm_fa(
    const AT* __restrict__ A, const unsigned short* __restrict__ BT,
    const float* __restrict__ bias0, void* out0, int ldc) {
  __shared__ __align__(16) unsigned short Bs[2][512 * 64];
  const int t = threadIdx.x;
  const int w = t >> 6, l = t & 63, li = l & 15, lg = l >> 4;
  const int wm = w >> 2, wn = w & 3;
  const int bid = blockIdx.x;
  const int m0 = (bid / NT) * 128, n0 = (bid % NT) * 512;
  const int K = 512;

  f32x4 acc[4][8] = {};

  const int st_row_base = (t >> 3);   // 0..63 within each i-group of 64 rows
  const int st_slot = t & 7;

  // ---- prologue: stage B(0), load A(0) ----
#pragma unroll
  for (int i = 0; i < 8; i++) {
    const int row = i * 64 + st_row_base;
    const int gs = (st_slot ^ (row & 7)) * 8;
    gload16(&BT[(size_t)(n0 + row) * K + gs], &Bs[0][(i * 512 + t) * 8]);
  }

  // A register prefetch (current K-tile), fragment layout per MFMA A-operand
  float4 a0f[4][2][2];  // fp32 path
  u16x8  a0b[4][2];     // bf16 path
#pragma unroll
  for (int mf = 0; mf < 4; mf++) {
    const size_t rbase = (size_t)(m0 + wm * 64 + mf * 16 + li) * K;
#pragma unroll
    for (int kk = 0; kk < 2; kk++) {
      if constexpr (sizeof(AT) == 4) {
        const float* src = (const float*)&A[rbase + kk * 32 + lg * 8];
        a0f[mf][kk][0] = *reinterpret_cast<const float4*>(src);
        a0f[mf][kk][1] = *reinterpret_cast<const float4*>(src + 4);
      } else {
        a0b[mf][kk] = *reinterpret_cast<const u16x8*>(&A[rbase + kk * 32 + lg * 8]);
      }
    }
  }
  __syncthreads();

  for (int kt = 0; kt < K; kt += 64) {
    const int cur = (kt >> 6) & 1;
    const bool more = (kt + 64) < K;
    // ---- stage B(t+1) early (latency hides under MFMA below) ----
    if (more) {
#pragma unroll
      for (int i = 0; i < 8; i++) {
        const int row = i * 64 + st_row_base;
        const int gs = (st_slot ^ (row & 7)) * 8;
        gload16(&BT[(size_t)(n0 + row) * K + kt + 64 + gs], &Bs[cur ^ 1][(i * 512 + t) * 8]);
      }
    }
    // ---- convert current A regs -> bf16 fragments ----
    bf16x8 af[4][2];
#pragma unroll
    for (int mf = 0; mf < 4; mf++)
#pragma unroll
      for (int kk = 0; kk < 2; kk++) {
        if constexpr (sizeof(AT) == 4) {
          bf16x8 v;
#pragma unroll
          for (int j = 0; j < 4; j++) {
            v[j]     = (__bf16)a0f[mf][kk][0][j];
            v[j + 4] = (__bf16)a0f[mf][kk][1][j];
          }
          af[mf][kk] = v;
        } else {
          af[mf][kk] = *reinterpret_cast<const bf16x8*>(&a0b[mf][kk]);
        }
      }
    // ---- prefetch A(t+1) into regs ----
    if (more) {
#pragma unroll
      for (int mf = 0; mf < 4; mf++) {
        const size_t rbase = (size_t)(m0 + wm * 64 + mf * 16 + li) * K + kt + 64;
#pragma unroll
        for (int kk = 0; kk < 2; kk++) {
          if constexpr (sizeof(AT) == 4) {
            const float* src = (const float*)&A[rbase + kk * 32 + lg * 8];
            a0f[mf][kk][0] = *reinterpret_cast<const float4*>(src);
            a0f[mf][kk][1] = *reinterpret_cast<const float4*>(src + 4);
          } else {
            a0b[mf][kk] = *reinterpret_cast<const u16x8*>(&A[rbase + kk * 32 + lg * 8]);
          }
        }
      }
    }
    // ---- MFMA over current tile ----
#pragma unroll
    for (int kk = 0; kk < 2; kk++) {
#pragma unroll
      for (int nf = 0; nf < 8; nf++) {
        const int row = wn * 128 + nf * 16 + li;
        const bf16x8 b = *reinterpret_cast<const bf16x8*>(
            &Bs[cur][row * 64 + (((kk * 4 + lg) ^ (row & 7)) * 8)]);
#pragma unroll
        for (int mf = 0; mf < 4; mf++)
          acc[mf][nf] = MFMA16(af[mf][kk], b, acc[mf][nf]);
      }
    }
    __syncthreads();  // drains vmcnt(0): B(t+1) LDS + A(t+1) regs complete
  }

  // ---- epilogue ----
  const int lg4 = lg * 4;
#pragma unroll
  for (int nf = 0; nf < 8; nf++) {
    const int col = n0 + wn * 128 + nf * 16 + li;
    const float bv = bias0[col];
#pragma unroll
    for (int mf = 0; mf < 4; mf++) {
      const int row = m0 + wm * 64 + mf * 16 + lg4;
      if constexpr (MODE == 0) {
        unsigned short* o = (unsigned short*)out0;
#pragma unroll
        for (int r = 0; r < 4; r++)
          o[(size_t)(row + r) * ldc + col] = f2bf_bits(acc[mf][nf][r] + bv);
      } else {
        float* o = (float*)out0;
#pragma unroll
        for (int r = 0; r < 4; r++)
          o[(size_t)(row + r) * ldc + col] = acc[mf][nf][r] + bv;
      }
    }
  }
}

// ---------------------------------------------------------------------------
// 128x128 bf16 GEMM (gload_lds) for the small kv/pc GEMM, N=1536 split output.
// ---------------------------------------------------------------------------
__global__ __launch_bounds__(256) void gemm_kvpc(
    const unsigned short* __restrict__ A, const unsigned short* __restrict__ BT,
    const float* __restrict__ bias0, const float* __restrict__ bias1,
    const float* __restrict__ bias2, unsigned short* out0, unsigned short* out1,
    float* out2, int Ntiles) {
  __shared__ __align__(16) unsigned short As[128 * 64];
  __shared__ __align__(16) unsigned short Bs[128 * 64];
  const int t = threadIdx.x;
  const int w = t >> 6, l = t & 63, li = l & 15, lg = l >> 4;
  const int wm = w >> 1, wn = w & 1;
  const int K = 512;
  const int m0 = (blockIdx.x / Ntiles) * 128, n0 = (blockIdx.x % Ntiles) * 128;

  f32x4 acc[4][4] = {};
  const int sr = t >> 3, sslot = t & 7;

  for (int kt = 0; kt < K; kt += 64) {
#pragma unroll
    for (int i = 0; i < 4; i++) {
      const int row = i * 32 + sr;
      const int gs = (sslot ^ (row & 7)) * 8;
      gload16(&A[(size_t)(m0 + row) * K + kt + gs], &As[(i * 256 + t) * 8]);
      gload16(&BT[(size_t)(n0 + row) * K + kt + gs], &Bs[(i * 256 + t) * 8]);
    }
    __syncthreads();
#pragma unroll
    for (int kk = 0; kk < 2; kk++) {
      bf16x8 a[4], b[4];
#pragma unroll
      for (int mf = 0; mf < 4; mf++) {
        const int r = wm * 64 + mf * 16 + li;
        a[mf] = *reinterpret_cast<const bf16x8*>(&As[r * 64 + (((kk * 4 + lg) ^ (r & 7)) * 8)]);
      }
#pragma unroll
      for (int nf = 0; nf < 4; nf++) {
        const int r = wn * 64 + nf * 16 + li;
        b[nf] = *reinterpret_cast<const bf16x8*>(&Bs[r * 64 + (((kk * 4 + lg) ^ (r & 7)) * 8)]);
      }
#pragma unroll
      for (int mf = 0; mf < 4; mf++)
#pragma unroll
        for (int nf = 0; nf < 4; nf++)
          acc[mf][nf] = MFMA16(a[mf], b[nf], acc[mf][nf]);
    }
    __syncthreads();
  }

  const int lg4 = lg * 4;
#pragma unroll
  for (int nf = 0; nf < 4; nf++) {
    const int col = n0 + wn * 64 + nf * 16 + li;
    if (col < 512) {
      const float bv = bias0[col];
#pragma unroll
      for (int mf = 0; mf < 4; mf++) {
        const int row = m0 + wm * 64 + mf * 16 + lg4;
#pragma unroll
        for (int r = 0; r < 4; r++)
          out0[(size_t)(row + r) * 512 + col] = f2bf_bits(acc[mf][nf][r] + bv);
      }
    } else if (col < 1024) {
      const float bv = bias1[col - 512];
#pragma unroll
      for (int mf = 0; mf < 4; mf++) {
        const int row = m0 + wm * 64 + mf * 16 + lg4;
#pragma unroll
        for (int r = 0; r < 4; r++)
          out1[(size_t)(row + r) * 512 + col - 512] = f2bf_bits(acc[mf][nf][r] + bv);
      }
    } else {
      const float bv = bias2[col - 1024];
#pragma unroll
      for (int mf = 0; mf < 4; mf++) {
        const int row = m0 + wm * 64 + mf * 16 + lg4;
#pragma unroll
        for (int r = 0; r < 4; r++)
          out2[(size_t)(row + r) * 512 + col - 1024] = acc[mf][nf][r] + bv;
      }
    }
  }
}

// ---------------------------------------------------------------------------
// fp32-A 128x128 GEMM (register-staged convert) — tiny pq projection only.
// ---------------------------------------------------------------------------
__global__ __launch_bounds__(256) void gemm_f32a(
    const float* __restrict__ A, const unsigned short* __restrict__ BT,
    const float* __restrict__ bias0, unsigned short* __restrict__ out,
    int K, int ldc) {
  __shared__ __align__(16) unsigned short As[128 * 72];
  __shared__ __align__(16) unsigned short Bs[128 * 72];
  const int t = threadIdx.x;
  const int w = t >> 6, l = t & 63, li = l & 15, lg = l >> 4;
  const int wm = w >> 1, wn = w & 1;
  const int m0 = blockIdx.x * 128, n0 = blockIdx.y * 128;

  f32x4 acc[4][4] = {};

  for (int kt = 0; kt < K; kt += 64) {
#pragma unroll
    for (int i = 0; i < 8; i++) {
      const int row = i * 16 + (t >> 4), k = (t & 15) * 4;
      const float4 v = *reinterpret_cast<const float4*>(&A[(size_t)(m0 + row) * K + kt + k]);
      u16x4 o;
      o[0] = f2bf_bits(v.x); o[1] = f2bf_bits(v.y);
      o[2] = f2bf_bits(v.z); o[3] = f2bf_bits(v.w);
      *reinterpret_cast<u16x4*>(&As[row * 72 + k]) = o;
    }
#pragma unroll
    for (int i = 0; i < 4; i++) {
      const int row = i * 32 + (t >> 3), k = (t & 7) * 8;
      const u16x8 v = *reinterpret_cast<const u16x8*>(&BT[(size_t)(n0 + row) * K + kt + k]);
      *reinterpret_cast<u16x8*>(&Bs[row * 72 + k]) = v;
    }
    __syncthreads();
#pragma unroll
    for (int kk = 0; kk < 2; kk++) {
      bf16x8 a[4], b[4];
#pragma unroll
      for (int mf = 0; mf < 4; mf++)
        a[mf] = *reinterpret_cast<const bf16x8*>(&As[(wm * 64 + mf * 16 + li) * 72 + kk * 32 + lg * 8]);
#pragma unroll
      for (int nf = 0; nf < 4; nf++)
        b[nf] = *reinterpret_cast<const bf16x8*>(&Bs[(wn * 64 + nf * 16 + li) * 72 + kk * 32 + lg * 8]);
#pragma unroll
      for (int mf = 0; mf < 4; mf++)
#pragma unroll
        for (int nf = 0; nf < 4; nf++)
          acc[mf][nf] = MFMA16(a[mf], b[nf], acc[mf][nf]);
    }
    __syncthreads();
  }
  const int lg4 = lg * 4;
#pragma unroll
  for (int nf = 0; nf < 4; nf++) {
    const int col = n0 + wn * 64 + nf * 16 + li;
    const float bv = bias0[col];
#pragma unroll
    for (int mf = 0; mf < 4; mf++) {
      const int row = m0 + wm * 64 + mf * 16 + lg4;
#pragma unroll
      for (int r = 0; r < 4; r++)
        out[(size_t)(row + r) * ldc + col] = f2bf_bits(acc[mf][nf][r] + bv);
    }
  }
}

// ---------------------------------------------------------------------------
// Pack attention, split over S. grid (128 bh, 8 chunks), block 256 (4 waves).
// ---------------------------------------------------------------------------
__global__ __launch_bounds__(256) void pack_attn(
    const unsigned short* __restrict__ pq_buf,
    const unsigned short* __restrict__ pkv_buf, float* __restrict__ partial) {
  __shared__ __align__(16) unsigned short pkL[64 * 72];
  __shared__ __align__(16) unsigned short pvT[64 * 72];
  __shared__ __align__(16) unsigned short prL[4 * 16 * 72];
  const int t = threadIdx.x, w = t >> 6, l = t & 63, li = l & 15, lg = l >> 4;
  const int bh = blockIdx.x, b = bh >> 3, h = bh & 7;
  const int sb = blockIdx.y * 512;

  bf16x8 aq[2];
  {
    const size_t base = ((size_t)(b * 64 + w * 16 + li)) * 512 + h * 64;
    aq[0] = *reinterpret_cast<const bf16x8*>(&pq_buf[base + lg * 8]);
    aq[1] = *reinterpret_cast<const bf16x8*>(&pq_buf[base + 32 + lg * 8]);
  }

  f32x4 acc[4] = {};
  float lsum[4] = {};

  for (int st = 0; st < 8; st++) {
    const int s0 = sb + st * 64;
#pragma unroll
    for (int i = 0; i < 2; i++) {
      const int row = i * 32 + (t >> 3), c = (t & 7) * 8;
      const u16x8 v = *reinterpret_cast<const u16x8*>(
          &pkv_buf[((size_t)(b * 4096 + s0 + row)) * 1024 + h * 64 + c]);
      *reinterpret_cast<u16x8*>(&pkL[row * 72 + c]) = v;
    }
    {
      const int rp = t >> 3, c = (t & 7) * 8;
      const size_t base = ((size_t)(b * 4096 + s0 + 2 * rp)) * 1024 + 512 + h * 64 + c;
      const u16x8 u0 = *reinterpret_cast<const u16x8*>(&pkv_buf[base]);
      const u16x8 u1 = *reinterpret_cast<const u16x8*>(&pkv_buf[base + 1024]);
#pragma unroll
      for (int j = 0; j < 8; j++) {
        const int val = ((int)u0[j] & 0xffff) | ((int)u1[j] << 16);
        *reinterpret_cast<int*>(&pvT[(c + j) * 72 + 2 * rp]) = val;
      }
    }
    __syncthreads();
    f32x4 sc[4] = {};
#pragma unroll
    for (int nf = 0; nf < 4; nf++) {
#pragma unroll
      for (int kk = 0; kk < 2; kk++) {
        const bf16x8 bk = *reinterpret_cast<const bf16x8*>(
            &pkL[(nf * 16 + li) * 72 + kk * 32 + lg * 8]);
        sc[nf] = MFMA16(aq[kk], bk, sc[nf]);
      }
    }
#pragma unroll
    for (int nf = 0; nf < 4; nf++) {
#pragma unroll
      for (int r = 0; r < 4; r++) {
        const float e = __expf(sc[nf][r]);
        lsum[r] += e;
        prL[(w * 16 + lg * 4 + r) * 72 + nf * 16 + li] = f2bf_bits(e);
      }
    }
#pragma unroll
    for (int kk = 0; kk < 2; kk++) {
      const bf16x8 ap = *reinterpret_cast<const bf16x8*>(
          &prL[(w * 16 + li) * 72 + kk * 32 + lg * 8]);
#pragma unroll
      for (int nf = 0; nf < 4; nf++) {
        const bf16x8 bv = *reinterpret_cast<const bf16x8*>(
            &pvT[(nf * 16 + li) * 72 + kk * 32 + lg * 8]);
        acc[nf] = MFMA16(ap, bv, acc[nf]);
      }
    }
    __syncthreads();
  }

#pragma unroll
  for (int m = 1; m < 16; m <<= 1)
#pragma unroll
    for (int r = 0; r < 4; r++) lsum[r] += __shfl_xor(lsum[r], m);

  const size_t pbase = ((size_t)(bh * 8 + blockIdx.y)) * 4160;
#pragma unroll
  for (int nf = 0; nf < 4; nf++)
#pragma unroll
    for (int r = 0; r < 4; r++)
      partial[pbase + (size_t)(w * 16 + lg * 4 + r) * 64 + nf * 16 + li] = acc[nf][r];
  if (li == 0)
#pragma unroll
    for (int r = 0; r < 4; r++) partial[pbase + 4096 + w * 16 + lg * 4 + r] = lsum[r];
}

__global__ __launch_bounds__(256) void pack_combine(const float* __restrict__ partial,
                                                    unsigned short* __restrict__ pc_buf) {
  const int bh = blockIdx.x, b = bh >> 3, h = bh & 7;
  const int t = threadIdx.x;
#pragma unroll
  for (int e = 0; e < 16; e++) {
    const int idx = e * 256 + t;
    const int p = idx >> 6, d = idx & 63;
    float s = 0.f, den = 0.f;
#pragma unroll
    for (int c = 0; c < 8; c++) {
      const float* pb = &partial[((size_t)(bh * 8 + c)) * 4160];
      s += pb[idx];
      den += pb[4096 + p];
    }
    pc_buf[((size_t)(b * 64 + p)) * 512 + h * 64 + d] = f2bf_bits(s / den);
  }
}

// ---------------------------------------------------------------------------
// Unpack attention. grid (16 s-tiles, 128 bh), block 256 (4 waves x 64 s-rows).
// ---------------------------------------------------------------------------
__global__ __launch_bounds__(256) void unpack_attn(
    const unsigned short* q_in, const unsigned short* __restrict__ k_buf,
    const unsigned short* __restrict__ v_buf, float* __restrict__ aw_out,
    unsigned short* attnh_out) {
  __shared__ __align__(16) unsigned short kL[64 * 72];
  __shared__ __align__(16) unsigned short vT[64 * 72];
  __shared__ __align__(16) unsigned short prL[4 * 64 * 72];
  const int t = threadIdx.x, w = t >> 6, l = t & 63, li = l & 15, lg = l >> 4;
  const int bh = blockIdx.y, b = bh >> 3, h = bh & 7;
  const int sbase = blockIdx.x * 256 + w * 64;

#pragma unroll
  for (int i = 0; i < 2; i++) {
    const int p = i * 32 + (t >> 3), c = (t & 7) * 8;
    const u16x8 v = *reinterpret_cast<const u16x8*>(
        &k_buf[((size_t)(b * 64 + p)) * 512 + h * 64 + c]);
    *reinterpret_cast<u16x8*>(&kL[p * 72 + c]) = v;
  }
  {
    const int rp = t >> 3, c = (t & 7) * 8;
    const size_t base = ((size_t)(b * 64 + 2 * rp)) * 512 + h * 64 + c;
    const u16x8 u0 = *reinterpret_cast<const u16x8*>(&v_buf[base]);
    const u16x8 u1 = *reinterpret_cast<const u16x8*>(&v_buf[base + 512]);
#pragma unroll
    for (int j = 0; j < 8; j++) {
      const int val = ((int)u0[j] & 0xffff) | ((int)u1[j] << 16);
      *reinterpret_cast<int*>(&vT[(c + j) * 72 + 2 * rp]) = val;
    }
  }
  bf16x8 aq[4][2];
#pragma unroll
  for (int mf = 0; mf < 4; mf++) {
    const size_t base = ((size_t)(b * 4096 + sbase + mf * 16 + li)) * 512 + h * 64;
    aq[mf][0] = *reinterpret_cast<const bf16x8*>(&q_in[base + lg * 8]);
    aq[mf][1] = *reinterpret_cast<const bf16x8*>(&q_in[base + 32 + lg * 8]);
  }
  __syncthreads();

  f32x4 sc[4][4] = {};
#pragma unroll
  for (int kk = 0; kk < 2; kk++)
#pragma unroll
    for (int nf = 0; nf < 4; nf++) {
      const bf16x8 bk = *reinterpret_cast<const bf16x8*>(
          &kL[(nf * 16 + li) * 72 + kk * 32 + lg * 8]);
#pragma unroll
      for (int mf = 0; mf < 4; mf++) sc[mf][nf] = MFMA16(aq[mf][kk], bk, sc[mf][nf]);
    }

#pragma unroll
  for (int mf = 0; mf < 4; mf++) {
#pragma unroll
    for (int r = 0; r < 4; r++) {
      float e[4];
      float rs = 0.f;
#pragma unroll
      for (int nf = 0; nf < 4; nf++) {
        e[nf] = __expf(sc[mf][nf][r]);
        rs += e[nf];
      }
#pragma unroll
      for (int m = 1; m < 16; m <<= 1) rs += __shfl_xor(rs, m);
      const float inv = 1.0f / rs;
      const int srow = sbase + mf * 16 + lg * 4 + r;
#pragma unroll
      for (int nf = 0; nf < 4; nf++) {
        const float pr = e[nf] * inv;
        aw_out[(size_t)srow * 8192 + bh * 64 + nf * 16 + li] = pr;
        prL[(w * 64 + mf * 16 + lg * 4 + r) * 72 + nf * 16 + li] = f2bf_bits(pr);
      }
    }
  }

  f32x4 acc[4][4] = {};
#pragma unroll
  for (int kk = 0; kk < 2; kk++)
#pragma unroll
    for (int mf = 0; mf < 4; mf++) {
      const bf16x8 ap = *reinterpret_cast<const bf16x8*>(
          &prL[(w * 64 + mf * 16 + li) * 72 + kk * 32 + lg * 8]);
#pragma unroll
      for (int nf = 0; nf < 4; nf++) {
        const bf16x8 bv = *reinterpret_cast<const bf16x8*>(
            &vT[(nf * 16 + li) * 72 + kk * 32 + lg * 8]);
        acc[mf][nf] = MFMA16(ap, bv, acc[mf][nf]);
      }
    }
#pragma unroll
  for (int mf = 0; mf < 4; mf++)
#pragma unroll
    for (int nf = 0; nf < 4; nf++)
#pragma unroll
      for (int r = 0; r < 4; r++)
        attnh_out[((size_t)(b * 4096 + sbase + mf * 16 + lg * 4 + r)) * 512 + h * 64 +
                  nf * 16 + li] = f2bf_bits(acc[mf][nf][r]);
}

// ---------------------------------------------------------------------------
extern "C" void kernel_launch(void* const* d_in, const int* in_sizes, int n_in,
                              void* d_out, int out_size, void* d_ws, size_t ws_size,
                              hipStream_t stream) {
  (void)in_sizes; (void)n_in; (void)out_size; (void)ws_size;

  const float* query   = (const float*)d_in[0];
  const float* pquery  = (const float*)d_in[1];
  const float* context = (const float*)d_in[2];
  const float* Wi  = (const float*)d_in[3];  const float* bi  = (const float*)d_in[4];
  const float* Wip = (const float*)d_in[5];  const float* bip = (const float*)d_in[6];
  const float* Wic = (const float*)d_in[7];  const float* bic = (const float*)d_in[8];
  const float* Wq  = (const float*)d_in[9];  const float* bq  = (const float*)d_in[10];
  const float* Wpq = (const float*)d_in[11]; const float* bpq = (const float*)d_in[12];
  const float* Wk  = (const float*)d_in[13]; const float* bk  = (const float*)d_in[14];
  const float* Wpk = (const float*)d_in[15]; const float* bpk = (const float*)d_in[16];
  const float* Wv  = (const float*)d_in[17]; const float* bv  = (const float*)d_in[18];
  const float* Wpv = (const float*)d_in[19]; const float* bpv = (const float*)d_in[20];
  const float* Wo  = (const float*)d_in[21]; const float* bo  = (const float*)d_in[22];
  const float* Wop = (const float*)d_in[23]; const float* bop = (const float*)d_in[24];

  // ---- workspace layout ----
  char* ws = (char*)d_ws;
  unsigned short* WT     = (unsigned short*)(ws);                 // 8 x 512x512 bf16
  unsigned short* WqeT   = (unsigned short*)(ws + 4u * 1024 * 1024);
  unsigned short* WpqeT  = WqeT + 512 * 512;
  unsigned short* WpkveT = WpqeT + 512 * 512;                     // 1024 x 512
  float* bqe   = (float*)(WpkveT + (size_t)1024 * 512);
  float* bpqe  = bqe + 512;
  float* bpkve = bpqe + 512;
  unsigned short* q_buf   = (unsigned short*)(ws + 8u * 1024 * 1024);  // 65536x512 (later attn_h)
  unsigned short* pkv_buf = q_buf + (size_t)65536 * 512;               // 65536x1024
  unsigned short* pq_buf  = pkv_buf + (size_t)65536 * 1024;
  unsigned short* pc_buf  = pq_buf + (size_t)1024 * 512;
  unsigned short* k_buf   = pc_buf + (size_t)1024 * 512;
  unsigned short* v_buf   = k_buf + (size_t)1024 * 512;
  float* partial = (float*)(v_buf + (size_t)1024 * 512);               // 1024 x 4160 f32

  float* out_attn = (float*)d_out;                       // (B,S,512) fp32
  float* out_pc   = out_attn + (size_t)16 * 4096 * 512;  // (B,P,512)
  float* out_aw   = out_pc + (size_t)16 * 64 * 512;      // (S,B*H,P)

  const dim3 blk(256);
  const dim3 blk512(512);

  // 1) weight prep
  Ptr8 tsrc; tsrc.p[0]=Wq; tsrc.p[1]=Wpq; tsrc.p[2]=Wpk; tsrc.p[3]=Wpv;
  tsrc.p[4]=Wk; tsrc.p[5]=Wv; tsrc.p[6]=Wop; tsrc.p[7]=Wo;
  transpose_w8<<<dim3(16, 16, 8), blk, 0, stream>>>(tsrc, WT);
  bias_all<<<dim3(2, 4), blk, 0, stream>>>(bi, bip, bic, Wq, Wpq, Wpk, Wpv,
                                           bq, bpq, bpk, bpv, bqe);
  gemm_wcomb<<<dim3(4, 4, 4), blk, 0, stream>>>(Wi, Wip, Wic, WT, WqeT);

  // 2) projections (A fp32 in registers, conv fused)
  gemm_fa<float, 0, 1><<<dim3(512), blk512, 0, stream>>>(
      query, WqeT, bqe, q_buf, 512);
  gemm_fa<float, 0, 2><<<dim3(1024), blk512, 0, stream>>>(
      context, WpkveT, bpkve, pkv_buf, 1024);
  gemm_f32a<<<dim3(8, 4), blk, 0, stream>>>(pquery, WpqeT, bpqe, pq_buf, 512, 512);

  // 3) pack attention (8 chunks) + combine -> pc
  pack_attn<<<dim3(128, 8), blk, 0, stream>>>(pq_buf, pkv_buf, partial);
  pack_combine<<<128, blk, 0, stream>>>(partial, pc_buf);

  // 4) k, v, pc_out (fused N=1536)
  gemm_kvpc<<<dim3(96), blk, 0, stream>>>(
      pc_buf, WT + (size_t)4 * 262144, bk, bv, bop, k_buf, v_buf, out_pc, 12);

  // 5) unpack attention: aw_t out + attn_h in-place over q_buf
  unpack_attn<<<dim3(16, 128), blk, 0, stream>>>(q_buf, k_buf, v_buf, out_aw, q_buf);

  // 6) final projection: attn = attn_h @ Wo + bo  (A bf16 in registers)
  gemm_fa<unsigned short, 1, 1><<<dim3(512), blk512, 0, stream>>>(
      q_buf, WT + (size_t)7 * 262144, bo, out_attn, 512);
}

// Round 4
// 525.678 us; speedup vs baseline: 1.5319x; 1.5319x over previous
//
#include <hip/hip_runtime.h>

// ---------------------------------------------------------------------------
// LUNA fused pipeline for MI355X / gfx950.  B=16, S=4096, P=64, QKV=512, H=8.
// R4: revert R3's spilling gemm_fa. Proven m97-style 128x128 GEMM everywhere;
//     NEW gemm_f32lds: A staged as fp32 via global_load_lds (conv kernel
//     eliminated; fp32->bf16 convert in VALU slack between ds_read and MFMA).
//     Launches 12 -> 10 (prep merge).  pack_attn 8 chunks.
// ---------------------------------------------------------------------------

typedef __bf16 bf16x8 __attribute__((ext_vector_type(8)));
typedef float f32x4 __attribute__((ext_vector_type(4)));
typedef unsigned short u16x8 __attribute__((ext_vector_type(8)));
typedef unsigned short u16x4 __attribute__((ext_vector_type(4)));

#define MFMA16(a, b, c) __builtin_amdgcn_mfma_f32_16x16x32_bf16((a), (b), (c), 0, 0, 0)

__device__ __forceinline__ unsigned short f2bf_bits(float f) {
  unsigned int u = __float_as_uint(f);
  u += 0x7fffu + ((u >> 16) & 1u);  // RTNE (finite inputs)
  return (unsigned short)(u >> 16);
}

__device__ __forceinline__ void gload16(const void* g, void* l) {
  __builtin_amdgcn_global_load_lds(
      (const __attribute__((address_space(1))) void*)g,
      (__attribute__((address_space(3))) void*)l, 16, 0, 0);
}

// ---------------------------------------------------------------------------
// prep: z 0..7 -> transpose+convert W_z into bf16 W^T; z==8 -> combined biases.
// grid (16,16,9), block 256.
// ---------------------------------------------------------------------------
struct Ptr8 { const float* p[8]; };

__global__ __launch_bounds__(256) void prep_kernel(
    Ptr8 srcs, unsigned short* __restrict__ WT,
    const float* bi, const float* bip, const float* bic,
    const float* Wq, const float* Wpq, const float* Wpk, const float* Wpv,
    const float* bq, const float* bpq, const float* bpk, const float* bpv,
    float* __restrict__ bias_out) {
  const int t = threadIdx.x;
  if (blockIdx.z < 8) {
    const float* __restrict__ W = srcs.p[blockIdx.z];
    unsigned short* __restrict__ O = WT + (size_t)blockIdx.z * 262144;
    __shared__ float tile[32][33];
    const int tr = blockIdx.x * 32, tc = blockIdx.y * 32;
    {
      const int r = t >> 3, c4 = (t & 7) * 4;
      const float4 v = *reinterpret_cast<const float4*>(&W[(size_t)(tr + r) * 512 + tc + c4]);
      tile[r][c4 + 0] = v.x; tile[r][c4 + 1] = v.y; tile[r][c4 + 2] = v.z; tile[r][c4 + 3] = v.w;
    }
    __syncthreads();
    {
      const int n = t >> 3, k4 = (t & 7) * 4;
      u16x4 o;
#pragma unroll
      for (int j = 0; j < 4; j++) o[j] = f2bf_bits(tile[k4 + j][n]);
      *reinterpret_cast<u16x4*>(&O[(size_t)(tc + n) * 512 + tr + k4]) = o;
    }
  } else {
    const int idx = blockIdx.y * 16 + blockIdx.x;
    if (idx >= 8) return;
    const int y = idx >> 1;
    const float* bin  = (y == 0) ? bi : (y == 1) ? bip : bic;
    const float* W    = (y == 0) ? Wq : (y == 1) ? Wpq : (y == 2) ? Wpk : Wpv;
    const float* bout = (y == 0) ? bq : (y == 1) ? bpq : (y == 2) ? bpk : bpv;
    const float scale = (y < 2) ? 0.125f : 1.0f;
    const int n = (idx & 1) * 256 + t;
    float s = 0.f;
    for (int k = 0; k < 512; k++) s += bin[k] * W[(size_t)k * 512 + n];
    bias_out[y * 512 + n] = (s + bout[n]) * scale;
  }
}

// ---------------------------------------------------------------------------
// Batched weight-combine: out_z^T = scale_z * (A_z @ WT_z^T), z in 0..3.
// ---------------------------------------------------------------------------
__global__ __launch_bounds__(256) void gemm_wcomb(
    const float* __restrict__ Wi, const float* __restrict__ Wip,
    const float* __restrict__ Wic, const unsigned short* __restrict__ WTbase,
    unsigned short* __restrict__ outbase) {
  const int z = blockIdx.z;
  const float* __restrict__ A = (z == 0) ? Wi : (z == 1) ? Wip : Wic;
  const unsigned short* __restrict__ BT = WTbase + (size_t)z * 262144;
  unsigned short* __restrict__ out = outbase + (size_t)z * 262144;
  const float scale = (z < 2) ? 0.125f : 1.0f;

  __shared__ __align__(16) unsigned short As[128 * 72];
  __shared__ __align__(16) unsigned short Bs[128 * 72];
  const int t = threadIdx.x;
  const int w = t >> 6, l = t & 63, li = l & 15, lg = l >> 4;
  const int wm = w >> 1, wn = w & 1;
  const int m0 = blockIdx.x * 128, n0 = blockIdx.y * 128;

  f32x4 acc[4][4] = {};

  for (int kt = 0; kt < 512; kt += 64) {
#pragma unroll
    for (int i = 0; i < 8; i++) {
      const int row = i * 16 + (t >> 4), k = (t & 15) * 4;
      const float4 v = *reinterpret_cast<const float4*>(&A[(size_t)(m0 + row) * 512 + kt + k]);
      u16x4 o;
      o[0] = f2bf_bits(v.x); o[1] = f2bf_bits(v.y);
      o[2] = f2bf_bits(v.z); o[3] = f2bf_bits(v.w);
      *reinterpret_cast<u16x4*>(&As[row * 72 + k]) = o;
    }
#pragma unroll
    for (int i = 0; i < 4; i++) {
      const int row = i * 32 + (t >> 3), k = (t & 7) * 8;
      const u16x8 v = *reinterpret_cast<const u16x8*>(&BT[(size_t)(n0 + row) * 512 + kt + k]);
      *reinterpret_cast<u16x8*>(&Bs[row * 72 + k]) = v;
    }
    __syncthreads();
#pragma unroll
    for (int kk = 0; kk < 2; kk++) {
      bf16x8 a[4], b[4];
#pragma unroll
      for (int mf = 0; mf < 4; mf++)
        a[mf] = *reinterpret_cast<const bf16x8*>(&As[(wm * 64 + mf * 16 + li) * 72 + kk * 32 + lg * 8]);
#pragma unroll
      for (int nf = 0; nf < 4; nf++)
        b[nf] = *reinterpret_cast<const bf16x8*>(&Bs[(wn * 64 + nf * 16 + li) * 72 + kk * 32 + lg * 8]);
#pragma unroll
      for (int mf = 0; mf < 4; mf++)
#pragma unroll
        for (int nf = 0; nf < 4; nf++)
          acc[mf][nf] = MFMA16(a[mf], b[nf], acc[mf][nf]);
    }
    __syncthreads();
  }
  const int lg4 = lg * 4;
#pragma unroll
  for (int nf = 0; nf < 4; nf++) {
    const int col = n0 + wn * 64 + nf * 16 + li;
#pragma unroll
    for (int mf = 0; mf < 4; mf++) {
      const int row = m0 + wm * 64 + mf * 16 + lg4;
#pragma unroll
      for (int r = 0; r < 4; r++)
        out[(size_t)col * 512 + row + r] = f2bf_bits(acc[mf][nf][r] * scale);
    }
  }
}

// ---------------------------------------------------------------------------
// gemm_f32lds: C[MxN] = bf16(A_fp32)[MxK] @ BT[NxK]^T + bias, bf16 out.
// 128x128 tile, BK=64, 256 threads (4 waves 2x2).  A staged as RAW FP32 via
// global_load_lds (pre-swizzled source, linear LDS dest); fp32->bf16 convert
// happens in registers after ds_read (uses GEMM's VALU slack).  B bf16 staged
// as in R2.  XCD-chunked 1D grid (gridDim.x % 8 == 0), n-tile fastest.
// ---------------------------------------------------------------------------
__global__ __launch_bounds__(256) void gemm_f32lds(
    const float* __restrict__ A, const unsigned short* __restrict__ BT,
    const float* __restrict__ bias0, unsigned short* __restrict__ out0,
    int Ntiles, int ldc) {
  __shared__ __align__(16) float Asf[128 * 64];          // 32 KB
  __shared__ __align__(16) unsigned short Bs[128 * 64];  // 16 KB
  const int t = threadIdx.x;
  const int w = t >> 6, l = t & 63, li = l & 15, lg = l >> 4;
  const int wm = w >> 1, wn = w & 1;
  const int K = 512;

  const int q8 = gridDim.x >> 3;
  const int wg = (blockIdx.x & 7) * q8 + (blockIdx.x >> 3);
  const int m0 = (wg / Ntiles) * 128, n0 = (wg % Ntiles) * 128;

  f32x4 acc[4][4] = {};

  const int arow = t >> 4, aslot = t & 15;  // A staging: 16 rows/iter x 16 slots
  const int brow = t >> 3, bslot = t & 7;   // B staging: 32 rows/iter x 8 slots

  for (int kt = 0; kt < K; kt += 64) {
    // ---- stage A fp32 tile (128 x 64 floats), source pre-swizzled ----
#pragma unroll
    for (int i = 0; i < 8; i++) {
      const int row = i * 16 + arow;
      const int gs = (aslot ^ (row & 15)) * 4;  // float offset within k-window
      gload16(&A[(size_t)(m0 + row) * K + kt + gs], &Asf[i * 1024 + t * 4]);
    }
    // ---- stage B bf16 tile (128 x 64) ----
#pragma unroll
    for (int i = 0; i < 4; i++) {
      const int row = i * 32 + brow;
      const int gs = (bslot ^ (row & 7)) * 8;
      gload16(&BT[(size_t)(n0 + row) * K + kt + gs], &Bs[(i * 256 + t) * 8]);
    }
    __syncthreads();  // compiler drains vmcnt(0) before s_barrier
#pragma unroll
    for (int kk = 0; kk < 2; kk++) {
      bf16x8 a[4], b[4];
#pragma unroll
      for (int mf = 0; mf < 4; mf++) {
        const int r = wm * 64 + mf * 16 + li;
        const int s0 = kk * 8 + lg * 2;
        const f32x4 lo = *reinterpret_cast<const f32x4*>(&Asf[r * 64 + ((s0 ^ (r & 15)) * 4)]);
        const f32x4 hi = *reinterpret_cast<const f32x4*>(&Asf[r * 64 + (((s0 + 1) ^ (r & 15)) * 4)]);
        bf16x8 v;
#pragma unroll
        for (int j = 0; j < 4; j++) { v[j] = (__bf16)lo[j]; v[j + 4] = (__bf16)hi[j]; }
        a[mf] = v;
      }
#pragma unroll
      for (int nf = 0; nf < 4; nf++) {
        const int r = wn * 64 + nf * 16 + li;
        b[nf] = *reinterpret_cast<const bf16x8*>(&Bs[r * 64 + (((kk * 4 + lg) ^ (r & 7)) * 8)]);
      }
#pragma unroll
      for (int mf = 0; mf < 4; mf++)
#pragma unroll
        for (int nf = 0; nf < 4; nf++)
          acc[mf][nf] = MFMA16(a[mf], b[nf], acc[mf][nf]);
    }
    __syncthreads();
  }

  const int lg4 = lg * 4;
#pragma unroll
  for (int nf = 0; nf < 4; nf++) {
    const int col = n0 + wn * 64 + nf * 16 + li;
    const float bv = bias0[col];
#pragma unroll
    for (int mf = 0; mf < 4; mf++) {
      const int row = m0 + wm * 64 + mf * 16 + lg4;
#pragma unroll
      for (int r = 0; r < 4; r++)
        out0[(size_t)(row + r) * ldc + col] = f2bf_bits(acc[mf][nf][r] + bv);
    }
  }
}

// ---------------------------------------------------------------------------
// m97-style bf16-A GEMM (R2-proven).  MODE 1: fp32 out+bias.
// MODE 2: N=1536 split -> bf16 out0+bias0 | bf16 out1+bias1 | fp32 out2+bias2.
// ---------------------------------------------------------------------------
template <int MODE>
__global__ __launch_bounds__(256) void gemm_bf16(
    const unsigned short* __restrict__ A, const unsigned short* __restrict__ BT,
    const float* __restrict__ bias0, const float* __restrict__ bias1,
    const float* __restrict__ bias2, void* out0, void* out1, void* out2,
    int Ntiles, int ldc) {
  __shared__ __align__(16) unsigned short As[128 * 64];
  __shared__ __align__(16) unsigned short Bs[128 * 64];
  const int t = threadIdx.x;
  const int w = t >> 6, l = t & 63, li = l & 15, lg = l >> 4;
  const int wm = w >> 1, wn = w & 1;
  const int K = 512;

  const int q8 = gridDim.x >> 3;
  const int wg = (blockIdx.x & 7) * q8 + (blockIdx.x >> 3);
  const int m0 = (wg / Ntiles) * 128, n0 = (wg % Ntiles) * 128;

  f32x4 acc[4][4] = {};
  const int sr = t >> 3, sslot = t & 7;

  for (int kt = 0; kt < K; kt += 64) {
#pragma unroll
    for (int i = 0; i < 4; i++) {
      const int row = i * 32 + sr;
      const int gs = (sslot ^ (row & 7)) * 8;
      gload16(&A[(size_t)(m0 + row) * K + kt + gs], &As[(i * 256 + t) * 8]);
      gload16(&BT[(size_t)(n0 + row) * K + kt + gs], &Bs[(i * 256 + t) * 8]);
    }
    __syncthreads();
#pragma unroll
    for (int kk = 0; kk < 2; kk++) {
      bf16x8 a[4], b[4];
#pragma unroll
      for (int mf = 0; mf < 4; mf++) {
        const int r = wm * 64 + mf * 16 + li;
        a[mf] = *reinterpret_cast<const bf16x8*>(&As[r * 64 + (((kk * 4 + lg) ^ (r & 7)) * 8)]);
      }
#pragma unroll
      for (int nf = 0; nf < 4; nf++) {
        const int r = wn * 64 + nf * 16 + li;
        b[nf] = *reinterpret_cast<const bf16x8*>(&Bs[r * 64 + (((kk * 4 + lg) ^ (r & 7)) * 8)]);
      }
#pragma unroll
      for (int mf = 0; mf < 4; mf++)
#pragma unroll
        for (int nf = 0; nf < 4; nf++)
          acc[mf][nf] = MFMA16(a[mf], b[nf], acc[mf][nf]);
    }
    __syncthreads();
  }

  const int lg4 = lg * 4;
#pragma unroll
  for (int nf = 0; nf < 4; nf++) {
    const int col = n0 + wn * 64 + nf * 16 + li;
    if constexpr (MODE == 1) {
      float* o = (float*)out0;
      const float bv = bias0[col];
#pragma unroll
      for (int mf = 0; mf < 4; mf++) {
        const int row = m0 + wm * 64 + mf * 16 + lg4;
#pragma unroll
        for (int r = 0; r < 4; r++)
          o[(size_t)(row + r) * ldc + col] = acc[mf][nf][r] + bv;
      }
    } else {  // MODE 2
      if (col < 512) {
        unsigned short* o = (unsigned short*)out0;
        const float bv = bias0[col];
#pragma unroll
        for (int mf = 0; mf < 4; mf++) {
          const int row = m0 + wm * 64 + mf * 16 + lg4;
#pragma unroll
          for (int r = 0; r < 4; r++)
            o[(size_t)(row + r) * 512 + col] = f2bf_bits(acc[mf][nf][r] + bv);
        }
      } else if (col < 1024) {
        unsigned short* o = (unsigned short*)out1;
        const float bv = bias1[col - 512];
#pragma unroll
        for (int mf = 0; mf < 4; mf++) {
          const int row = m0 + wm * 64 + mf * 16 + lg4;
#pragma unroll
          for (int r = 0; r < 4; r++)
            o[(size_t)(row + r) * 512 + col - 512] = f2bf_bits(acc[mf][nf][r] + bv);
        }
      } else {
        float* o = (float*)out2;
        const float bv = bias2[col - 1024];
#pragma unroll
        for (int mf = 0; mf < 4; mf++) {
          const int row = m0 + wm * 64 + mf * 16 + lg4;
#pragma unroll
          for (int r = 0; r < 4; r++)
            o[(size_t)(row + r) * 512 + col - 1024] = acc[mf][nf][r] + bv;
        }
      }
    }
  }
}

// ---------------------------------------------------------------------------
// fp32-A 128x128 GEMM (register-staged convert) — tiny pq projection only.
// ---------------------------------------------------------------------------
__global__ __launch_bounds__(256) void gemm_f32a(
    const float* __restrict__ A, const unsigned short* __restrict__ BT,
    const float* __restrict__ bias0, unsigned short* __restrict__ out,
    int K, int ldc) {
  __shared__ __align__(16) unsigned short As[128 * 72];
  __shared__ __align__(16) unsigned short Bs[128 * 72];
  const int t = threadIdx.x;
  const int w = t >> 6, l = t & 63, li = l & 15, lg = l >> 4;
  const int wm = w >> 1, wn = w & 1;
  const int m0 = blockIdx.x * 128, n0 = blockIdx.y * 128;

  f32x4 acc[4][4] = {};

  for (int kt = 0; kt < K; kt += 64) {
#pragma unroll
    for (int i = 0; i < 8; i++) {
      const int row = i * 16 + (t >> 4), k = (t & 15) * 4;
      const float4 v = *reinterpret_cast<const float4*>(&A[(size_t)(m0 + row) * K + kt + k]);
      u16x4 o;
      o[0] = f2bf_bits(v.x); o[1] = f2bf_bits(v.y);
      o[2] = f2bf_bits(v.z); o[3] = f2bf_bits(v.w);
      *reinterpret_cast<u16x4*>(&As[row * 72 + k]) = o;
    }
#pragma unroll
    for (int i = 0; i < 4; i++) {
      const int row = i * 32 + (t >> 3), k = (t & 7) * 8;
      const u16x8 v = *reinterpret_cast<const u16x8*>(&BT[(size_t)(n0 + row) * K + kt + k]);
      *reinterpret_cast<u16x8*>(&Bs[row * 72 + k]) = v;
    }
    __syncthreads();
#pragma unroll
    for (int kk = 0; kk < 2; kk++) {
      bf16x8 a[4], b[4];
#pragma unroll
      for (int mf = 0; mf < 4; mf++)
        a[mf] = *reinterpret_cast<const bf16x8*>(&As[(wm * 64 + mf * 16 + li) * 72 + kk * 32 + lg * 8]);
#pragma unroll
      for (int nf = 0; nf < 4; nf++)
        b[nf] = *reinterpret_cast<const bf16x8*>(&Bs[(wn * 64 + nf * 16 + li) * 72 + kk * 32 + lg * 8]);
#pragma unroll
      for (int mf = 0; mf < 4; mf++)
#pragma unroll
        for (int nf = 0; nf < 4; nf++)
          acc[mf][nf] = MFMA16(a[mf], b[nf], acc[mf][nf]);
    }
    __syncthreads();
  }
  const int lg4 = lg * 4;
#pragma unroll
  for (int nf = 0; nf < 4; nf++) {
    const int col = n0 + wn * 64 + nf * 16 + li;
    const float bv = bias0[col];
#pragma unroll
    for (int mf = 0; mf < 4; mf++) {
      const int row = m0 + wm * 64 + mf * 16 + lg4;
#pragma unroll
      for (int r = 0; r < 4; r++)
        out[(size_t)(row + r) * ldc + col] = f2bf_bits(acc[mf][nf][r] + bv);
    }
  }
}

// ---------------------------------------------------------------------------
// Pack attention, split over S. grid (128 bh, 8 chunks), block 256 (4 waves).
// ---------------------------------------------------------------------------
__global__ __launch_bounds__(256) void pack_attn(
    const unsigned short* __restrict__ pq_buf,
    const unsigned short* __restrict__ pkv_buf, float* __restrict__ partial) {
  __shared__ __align__(16) unsigned short pkL[64 * 72];
  __shared__ __align__(16) unsigned short pvT[64 * 72];
  __shared__ __align__(16) unsigned short prL[4 * 16 * 72];
  const int t = threadIdx.x, w = t >> 6, l = t & 63, li = l & 15, lg = l >> 4;
  const int bh = blockIdx.x, b = bh >> 3, h = bh & 7;
  const int sb = blockIdx.y * 512;

  bf16x8 aq[2];
  {
    const size_t base = ((size_t)(b * 64 + w * 16 + li)) * 512 + h * 64;
    aq[0] = *reinterpret_cast<const bf16x8*>(&pq_buf[base + lg * 8]);
    aq[1] = *reinterpret_cast<const bf16x8*>(&pq_buf[base + 32 + lg * 8]);
  }

  f32x4 acc[4] = {};
  float lsum[4] = {};

  for (int st = 0; st < 8; st++) {
    const int s0 = sb + st * 64;
#pragma unroll
    for (int i = 0; i < 2; i++) {
      const int row = i * 32 + (t >> 3), c = (t & 7) * 8;
      const u16x8 v = *reinterpret_cast<const u16x8*>(
          &pkv_buf[((size_t)(b * 4096 + s0 + row)) * 1024 + h * 64 + c]);
      *reinterpret_cast<u16x8*>(&pkL[row * 72 + c]) = v;
    }
    {
      const int rp = t >> 3, c = (t & 7) * 8;
      const size_t base = ((size_t)(b * 4096 + s0 + 2 * rp)) * 1024 + 512 + h * 64 + c;
      const u16x8 u0 = *reinterpret_cast<const u16x8*>(&pkv_buf[base]);
      const u16x8 u1 = *reinterpret_cast<const u16x8*>(&pkv_buf[base + 1024]);
#pragma unroll
      for (int j = 0; j < 8; j++) {
        const int val = ((int)u0[j] & 0xffff) | ((int)u1[j] << 16);
        *reinterpret_cast<int*>(&pvT[(c + j) * 72 + 2 * rp]) = val;
      }
    }
    __syncthreads();
    f32x4 sc[4] = {};
#pragma unroll
    for (int nf = 0; nf < 4; nf++) {
#pragma unroll
      for (int kk = 0; kk < 2; kk++) {
        const bf16x8 bk = *reinterpret_cast<const bf16x8*>(
            &pkL[(nf * 16 + li) * 72 + kk * 32 + lg * 8]);
        sc[nf] = MFMA16(aq[kk], bk, sc[nf]);
      }
    }
#pragma unroll
    for (int nf = 0; nf < 4; nf++) {
#pragma unroll
      for (int r = 0; r < 4; r++) {
        const float e = __expf(sc[nf][r]);
        lsum[r] += e;
        prL[(w * 16 + lg * 4 + r) * 72 + nf * 16 + li] = f2bf_bits(e);
      }
    }
#pragma unroll
    for (int kk = 0; kk < 2; kk++) {
      const bf16x8 ap = *reinterpret_cast<const bf16x8*>(
          &prL[(w * 16 + li) * 72 + kk * 32 + lg * 8]);
#pragma unroll
      for (int nf = 0; nf < 4; nf++) {
        const bf16x8 bv = *reinterpret_cast<const bf16x8*>(
            &pvT[(nf * 16 + li) * 72 + kk * 32 + lg * 8]);
        acc[nf] = MFMA16(ap, bv, acc[nf]);
      }
    }
    __syncthreads();
  }

#pragma unroll
  for (int m = 1; m < 16; m <<= 1)
#pragma unroll
    for (int r = 0; r < 4; r++) lsum[r] += __shfl_xor(lsum[r], m);

  const size_t pbase = ((size_t)(bh * 8 + blockIdx.y)) * 4160;
#pragma unroll
  for (int nf = 0; nf < 4; nf++)
#pragma unroll
    for (int r = 0; r < 4; r++)
      partial[pbase + (size_t)(w * 16 + lg * 4 + r) * 64 + nf * 16 + li] = acc[nf][r];
  if (li == 0)
#pragma unroll
    for (int r = 0; r < 4; r++) partial[pbase + 4096 + w * 16 + lg * 4 + r] = lsum[r];
}

__global__ __launch_bounds__(256) void pack_combine(const float* __restrict__ partial,
                                                    unsigned short* __restrict__ pc_buf) {
  const int bh = blockIdx.x, b = bh >> 3, h = bh & 7;
  const int t = threadIdx.x;
#pragma unroll
  for (int e = 0; e < 16; e++) {
    const int idx = e * 256 + t;
    const int p = idx >> 6, d = idx & 63;
    float s = 0.f, den = 0.f;
#pragma unroll
    for (int c = 0; c < 8; c++) {
      const float* pb = &partial[((size_t)(bh * 8 + c)) * 4160];
      s += pb[idx];
      den += pb[4096 + p];
    }
    pc_buf[((size_t)(b * 64 + p)) * 512 + h * 64 + d] = f2bf_bits(s / den);
  }
}

// ---------------------------------------------------------------------------
// Unpack attention. grid (16 s-tiles, 128 bh), block 256 (4 waves x 64 s-rows).
// ---------------------------------------------------------------------------
__global__ __launch_bounds__(256) void unpack_attn(
    const unsigned short* q_in, const unsigned short* __restrict__ k_buf,
    const unsigned short* __restrict__ v_buf, float* __restrict__ aw_out,
    unsigned short* attnh_out) {
  __shared__ __align__(16) unsigned short kL[64 * 72];
  __shared__ __align__(16) unsigned short vT[64 * 72];
  __shared__ __align__(16) unsigned short prL[4 * 64 * 72];
  const int t = threadIdx.x, w = t >> 6, l = t & 63, li = l & 15, lg = l >> 4;
  const int bh = blockIdx.y, b = bh >> 3, h = bh & 7;
  const int sbase = blockIdx.x * 256 + w * 64;

#pragma unroll
  for (int i = 0; i < 2; i++) {
    const int p = i * 32 + (t >> 3), c = (t & 7) * 8;
    const u16x8 v = *reinterpret_cast<const u16x8*>(
        &k_buf[((size_t)(b * 64 + p)) * 512 + h * 64 + c]);
    *reinterpret_cast<u16x8*>(&kL[p * 72 + c]) = v;
  }
  {
    const int rp = t >> 3, c = (t & 7) * 8;
    const size_t base = ((size_t)(b * 64 + 2 * rp)) * 512 + h * 64 + c;
    const u16x8 u0 = *reinterpret_cast<const u16x8*>(&v_buf[base]);
    const u16x8 u1 = *reinterpret_cast<const u16x8*>(&v_buf[base + 512]);
#pragma unroll
    for (int j = 0; j < 8; j++) {
      const int val = ((int)u0[j] & 0xffff) | ((int)u1[j] << 16);
      *reinterpret_cast<int*>(&vT[(c + j) * 72 + 2 * rp]) = val;
    }
  }
  bf16x8 aq[4][2];
#pragma unroll
  for (int mf = 0; mf < 4; mf++) {
    const size_t base = ((size_t)(b * 4096 + sbase + mf * 16 + li)) * 512 + h * 64;
    aq[mf][0] = *reinterpret_cast<const bf16x8*>(&q_in[base + lg * 8]);
    aq[mf][1] = *reinterpret_cast<const bf16x8*>(&q_in[base + 32 + lg * 8]);
  }
  __syncthreads();

  f32x4 sc[4][4] = {};
#pragma unroll
  for (int kk = 0; kk < 2; kk++)
#pragma unroll
    for (int nf = 0; nf < 4; nf++) {
      const bf16x8 bk = *reinterpret_cast<const bf16x8*>(
          &kL[(nf * 16 + li) * 72 + kk * 32 + lg * 8]);
#pragma unroll
      for (int mf = 0; mf < 4; mf++) sc[mf][nf] = MFMA16(aq[mf][kk], bk, sc[mf][nf]);
    }

#pragma unroll
  for (int mf = 0; mf < 4; mf++) {
#pragma unroll
    for (int r = 0; r < 4; r++) {
      float e[4];
      float rs = 0.f;
#pragma unroll
      for (int nf = 0; nf < 4; nf++) {
        e[nf] = __expf(sc[mf][nf][r]);
        rs += e[nf];
      }
#pragma unroll
      for (int m = 1; m < 16; m <<= 1) rs += __shfl_xor(rs, m);
      const float inv = 1.0f / rs;
      const int srow = sbase + mf * 16 + lg * 4 + r;
#pragma unroll
      for (int nf = 0; nf < 4; nf++) {
        const float pr = e[nf] * inv;
        aw_out[(size_t)srow * 8192 + bh * 64 + nf * 16 + li] = pr;
        prL[(w * 64 + mf * 16 + lg * 4 + r) * 72 + nf * 16 + li] = f2bf_bits(pr);
      }
    }
  }

  f32x4 acc[4][4] = {};
#pragma unroll
  for (int kk = 0; kk < 2; kk++)
#pragma unroll
    for (int mf = 0; mf < 4; mf++) {
      const bf16x8 ap = *reinterpret_cast<const bf16x8*>(
          &prL[(w * 64 + mf * 16 + li) * 72 + kk * 32 + lg * 8]);
#pragma unroll
      for (int nf = 0; nf < 4; nf++) {
        const bf16x8 bv = *reinterpret_cast<const bf16x8*>(
            &vT[(nf * 16 + li) * 72 + kk * 32 + lg * 8]);
        acc[mf][nf] = MFMA16(ap, bv, acc[mf][nf]);
      }
    }
#pragma unroll
  for (int mf = 0; mf < 4; mf++)
#pragma unroll
    for (int nf = 0; nf < 4; nf++)
#pragma unroll
      for (int r = 0; r < 4; r++)
        attnh_out[((size_t)(b * 4096 + sbase + mf * 16 + lg * 4 + r)) * 512 + h * 64 +
                  nf * 16 + li] = f2bf_bits(acc[mf][nf][r]);
}

// ---------------------------------------------------------------------------
extern "C" void kernel_launch(void* const* d_in, const int* in_sizes, int n_in,
                              void* d_out, int out_size, void* d_ws, size_t ws_size,
                              hipStream_t stream) {
  (void)in_sizes; (void)n_in; (void)out_size; (void)ws_size;

  const float* query   = (const float*)d_in[0];
  const float* pquery  = (const float*)d_in[1];
  const float* context = (const float*)d_in[2];
  const float* Wi  = (const float*)d_in[3];  const float* bi  = (const float*)d_in[4];
  const float* Wip = (const float*)d_in[5];  const float* bip = (const float*)d_in[6];
  const float* Wic = (const float*)d_in[7];  const float* bic = (const float*)d_in[8];
  const float* Wq  = (const float*)d_in[9];  const float* bq  = (const float*)d_in[10];
  const float* Wpq = (const float*)d_in[11]; const float* bpq = (const float*)d_in[12];
  const float* Wk  = (const float*)d_in[13]; const float* bk  = (const float*)d_in[14];
  const float* Wpk = (const float*)d_in[15]; const float* bpk = (const float*)d_in[16];
  const float* Wv  = (const float*)d_in[17]; const float* bv  = (const float*)d_in[18];
  const float* Wpv = (const float*)d_in[19]; const float* bpv = (const float*)d_in[20];
  const float* Wo  = (const float*)d_in[21]; const float* bo  = (const float*)d_in[22];
  const float* Wop = (const float*)d_in[23]; const float* bop = (const float*)d_in[24];

  // ---- workspace layout ----
  char* ws = (char*)d_ws;
  unsigned short* WT     = (unsigned short*)(ws);                 // 8 x 512x512 bf16
  unsigned short* WqeT   = (unsigned short*)(ws + 4u * 1024 * 1024);
  unsigned short* WpqeT  = WqeT + 512 * 512;
  unsigned short* WpkveT = WpqeT + 512 * 512;                     // 1024 x 512
  float* bqe   = (float*)(WpkveT + (size_t)1024 * 512);
  float* bpqe  = bqe + 512;
  float* bpkve = bpqe + 512;
  unsigned short* q_buf   = (unsigned short*)(ws + 8u * 1024 * 1024);  // 65536x512 (later attn_h)
  unsigned short* pkv_buf = q_buf + (size_t)65536 * 512;               // 65536x1024
  unsigned short* pq_buf  = pkv_buf + (size_t)65536 * 1024;
  unsigned short* pc_buf  = pq_buf + (size_t)1024 * 512;
  unsigned short* k_buf   = pc_buf + (size_t)1024 * 512;
  unsigned short* v_buf   = k_buf + (size_t)1024 * 512;
  float* partial = (float*)(v_buf + (size_t)1024 * 512);               // 1024 x 4160 f32

  float* out_attn = (float*)d_out;                       // (B,S,512) fp32
  float* out_pc   = out_attn + (size_t)16 * 4096 * 512;  // (B,P,512)
  float* out_aw   = out_pc + (size_t)16 * 64 * 512;      // (S,B*H,P)

  const dim3 blk(256);

  // 1) weight prep: transposes + combined biases in one launch, then combine
  Ptr8 tsrc; tsrc.p[0]=Wq; tsrc.p[1]=Wpq; tsrc.p[2]=Wpk; tsrc.p[3]=Wpv;
  tsrc.p[4]=Wk; tsrc.p[5]=Wv; tsrc.p[6]=Wop; tsrc.p[7]=Wo;
  prep_kernel<<<dim3(16, 16, 9), blk, 0, stream>>>(
      tsrc, WT, bi, bip, bic, Wq, Wpq, Wpk, Wpv, bq, bpq, bpk, bpv, bqe);
  gemm_wcomb<<<dim3(4, 4, 4), blk, 0, stream>>>(Wi, Wip, Wic, WT, WqeT);

  // 2) projections — fp32 A staged directly to LDS (no conv pass)
  gemm_f32lds<<<dim3(2048), blk, 0, stream>>>(query, WqeT, bqe, q_buf, 4, 512);
  gemm_f32lds<<<dim3(4096), blk, 0, stream>>>(context, WpkveT, bpkve, pkv_buf, 8, 1024);
  gemm_f32a<<<dim3(8, 4), blk, 0, stream>>>(pquery, WpqeT, bpqe, pq_buf, 512, 512);

  // 3) pack attention (8 chunks) + combine -> pc
  pack_attn<<<dim3(128, 8), blk, 0, stream>>>(pq_buf, pkv_buf, partial);
  pack_combine<<<128, blk, 0, stream>>>(partial, pc_buf);

  // 4) k, v, pc_out (fused N=1536)
  gemm_bf16<2><<<dim3(96), blk, 0, stream>>>(
      pc_buf, WT + (size_t)4 * 262144, bk, bv, bop, k_buf, v_buf, out_pc, 12, 512);

  // 5) unpack attention: aw_t out + attn_h in-place over q_buf
  unpack_attn<<<dim3(16, 128), blk, 0, stream>>>(q_buf, k_buf, v_buf, out_aw, q_buf);

  // 6) final projection: attn = attn_h @ Wo + bo
  gemm_bf16<1><<<dim3(2048), blk, 0, stream>>>(
      q_buf, WT + (size_t)7 * 262144, bo, nullptr, nullptr, out_attn, nullptr, nullptr,
      4, 512);
}